// Round 3
// baseline (157.686 us; speedup 1.0000x reference)
//
#include <hip/hip_runtime.h>

// RoundRobinGate: output = (0.0 scalar, one-hot [2,4096,16,512] f32, same tensor as bool->f32).
// Fully input-independent: 537 MB of zeros + 16,384 ones. Pure store-BW problem.
//
// Single fused fill kernel shaped like rocclr fillBufferAligned (proven 6.55-6.85 TB/s):
// each thread stores 8 consecutive float4s (128 B) per span-pass from one base address
// (immediate offsets 0..112), with the rare hot quad substituted inline via uniform
// scalar compares.
//
// Flat layout (float32), NTOT = 1 + 2*N1 elements:
//   p = 0                  -> scalar 0.0
//   p in [1, 1+N1)         -> dense one-hot, j = p-1
//   p in [1+N1, 1+2*N1)    -> identical content
// Row (t,g,i): base element 1 + t*N1 + g*2^25 + i*8192, hot col = ((i&15)<<9)|(i>>4).
// Span r (r = t*8192 + g*4096 + i) = elements [8192r, 8192(r+1)): holds offset-8191
// element of row r-1 (never hot, since hot <= 7935) or the scalar (r=0), plus the
// first 8191 elements of row r including its hot at span offset hl = hot+1.
// Tail element 134217728 (offset 8191 of row 16383) is never hot -> 0.0.

#define NROWS 16384u
#define ROWS_PER_BLOCK 8u
#define NBLOCKS 2048u

__global__ void __launch_bounds__(256) rr_gate_fused(float4* __restrict__ out4,
                                                     float* __restrict__ out) {
    const unsigned tid = threadIdx.x;
    const unsigned r0  = blockIdx.x * ROWS_PER_BLOCK;
    const float4 zero = make_float4(0.0f, 0.0f, 0.0f, 0.0f);

    for (unsigned rr = 0; rr < ROWS_PER_BLOCK; ++rr) {
        const unsigned r = r0 + rr;
        // ---- uniform per-span scalar math ----
        const unsigned i   = r & 4095u;                       // token row
        const unsigned hot = ((i & 15u) << 9) | (i >> 4);     // expert*512 + slot
        const unsigned hl  = hot + 1u;                        // element offset in span
        const unsigned qh  = hl >> 2;                         // hot quad in span [0,2048)
        const unsigned ht  = qh >> 3;                         // owning thread
        const unsigned sl  = qh & 7u;                         // slot within thread's 8 quads
        const unsigned comp = hl & 3u;                        // component within quad
        float4 hv;
        hv.x = (comp == 0u) ? 1.0f : 0.0f;
        hv.y = (comp == 1u) ? 1.0f : 0.0f;
        hv.z = (comp == 2u) ? 1.0f : 0.0f;
        hv.w = (comp == 3u) ? 1.0f : 0.0f;

        // ---- fill: 8 consecutive quads (128 B) per thread, imm offsets ----
        float4* base = out4 + ((size_t)r << 11) + (size_t)tid * 8u;
        const bool own = (tid == ht);
#pragma unroll
        for (unsigned k = 0; k < 8u; ++k) {
            float4 v = (own && k == sl) ? hv : zero;
            base[k] = v;
        }
    }
    // Final odd element (index 1 + 2*N1 - 1 = 134217728): always 0.
    if (blockIdx.x == 0 && tid == 0) {
        out[134217728u] = 0.0f;
    }
}

extern "C" void kernel_launch(void* const* d_in, const int* in_sizes, int n_in,
                              void* d_out, int out_size, void* d_ws, size_t ws_size,
                              hipStream_t stream) {
    (void)d_in; (void)in_sizes; (void)n_in; (void)d_ws; (void)ws_size; (void)out_size;
    hipLaunchKernelGGL(rr_gate_fused, dim3(NBLOCKS), dim3(256), 0, stream,
                       (float4*)d_out, (float*)d_out);
}

// Round 4
// 100.995 us; speedup vs baseline: 1.5613x; 1.5613x over previous
//
#include <hip/hip_runtime.h>

// RoundRobinGate: output = (0.0 scalar, one-hot [2,4096,16,512] f32, same tensor as
// bool->f32). Fully input-independent: 537 MB of zeros + 16,384 ones. Pure store-BW.
//
// Single coalesced fill kernel. Flat layout (float32), NTOT = 1 + 2*N1:
//   p = 0               -> scalar 0.0
//   p in [1, 1+N1)      -> dense one-hot, j = p-1
//   p in [1+N1, 1+2N1)  -> identical content
// Span r (= p>>13, r in [0,16384)) covers elements [8192r, 8192(r+1)):
//   element 8192r is row r-1's offset 8191 (never hot: hot <= 7935) or the p=0 scalar;
//   elements 8192r+1.. are row r's offsets 0..8190 including its hot at span offset
//   hl = hot+1, where i = r & 4095 and hot = ((i&15)<<9)|(i>>4).
// Tail element p = 134217728 (row 16383 offset 8191) is never hot -> 0.0.
//
// One block per span; 256 threads x 8 passes of lane-contiguous float4 stores
// (lane i stores quad tid + m*256 -> fully coalesced 4 KB per wave-instruction).
// Hot quad substituted on the single scalar-matching pass (m == owner_m).

__global__ void __launch_bounds__(256) rr_gate_fill(float4* __restrict__ out4,
                                                    float* __restrict__ out) {
    const unsigned r   = blockIdx.x;          // span id [0, 16384)
    const unsigned tid = threadIdx.x;

    // ---- wave-uniform scalar math ----
    const unsigned i       = r & 4095u;                   // token row
    const unsigned hot     = ((i & 15u) << 9) | (i >> 4); // expert*512 + slot
    const unsigned hl      = hot + 1u;                    // hot offset within span
    const unsigned qh      = hl >> 2;                     // hot quad within span [0,1985)
    const unsigned owner_m = qh >> 8;                     // which of the 8 passes
    const unsigned ht      = qh & 255u;                   // owning thread
    const unsigned comp    = hl & 3u;                     // component within quad

    float4 hv;
    hv.x = (comp == 0u) ? 1.0f : 0.0f;
    hv.y = (comp == 1u) ? 1.0f : 0.0f;
    hv.z = (comp == 2u) ? 1.0f : 0.0f;
    hv.w = (comp == 3u) ? 1.0f : 0.0f;
    const float4 zero = make_float4(0.0f, 0.0f, 0.0f, 0.0f);
    const bool own = (tid == ht);

    float4* base = out4 + ((size_t)r << 11) + tid;
#pragma unroll
    for (unsigned m = 0; m < 8u; ++m) {
        float4 v = (m == owner_m && own) ? hv : zero;
        base[(size_t)m * 256u] = v;
    }

    // Final odd element (index 1 + 2*N1 - 1 = 134217728): always 0.
    if (r == 0 && tid == 0) {
        out[134217728u] = 0.0f;
    }
}

extern "C" void kernel_launch(void* const* d_in, const int* in_sizes, int n_in,
                              void* d_out, int out_size, void* d_ws, size_t ws_size,
                              hipStream_t stream) {
    (void)d_in; (void)in_sizes; (void)n_in; (void)d_ws; (void)ws_size; (void)out_size;
    hipLaunchKernelGGL(rr_gate_fill, dim3(16384), dim3(256), 0, stream,
                       (float4*)d_out, (float*)d_out);
}